// Round 3
// baseline (370.818 us; speedup 1.0000x reference)
//
#include <hip/hip_runtime.h>

// CASSI forward: y[m, n+l] += x[m,n,l] * ca[m,n]
// x: (1, M, N, L) fp32, ca: (1, M, N, 1) fp32, y: (1, M, N+L-1, 1) fp32
//
// R2 post-mortem: gather-from-LDS fixed the atomic disaster (338->~116 us
// kernel) but the stage->barrier->gather->barrier phase structure leaves HBM
// idle during gather phases (4 blocks/CU can't cover). R3: register-buffer
// software pipeline — issue chunk c+1's global loads before gathering chunk
// c, so HBM latency hides under gather compute. LDS layout unchanged
// (P=65 padded stride: staging writes and diagonal gather reads are both
// <=2-way bank aliased = free per m136).

#define CASSI_M 1024
#define CASSI_N 1024
#define CASSI_L 64
#define CASSI_OUTW (CASSI_N + CASSI_L - 1)  // 1087

constexpr int CN = 128;              // n-chunk per LDS tile
constexpr int P = CASSI_L + 1;       // 65: padded LDS stride (floats)
constexpr int NCHUNK = CASSI_N / CN; // 8
constexpr int OPT = 5;               // output columns per thread
constexpr int SPC = (CN * CASSI_L) / (256 * 4);  // 8 float4 per thread/chunk

__global__ __launch_bounds__(256) void cassi_pipe_kernel(
    const float* __restrict__ x, const float* __restrict__ ca,
    float* __restrict__ out) {
    __shared__ float xs[CN * P];     // 33,280 B -> 4 blocks/CU

    const int m = blockIdx.x;
    const int t = threadIdx.x;

    const float* __restrict__ xrow = x + (size_t)m * (CASSI_N * CASSI_L);
    const float* __restrict__ carow = ca + (size_t)m * CASSI_N;

    float4 vbuf[SPC];                // prefetch register buffer (32 VGPRs)
    float  cbuf[SPC];

    // preload chunk 0
#pragma unroll
    for (int s = 0; s < SPC; ++s) {
        const int f = (s * 256 + t) * 4;
        vbuf[s] = *reinterpret_cast<const float4*>(xrow + f);
        cbuf[s] = carow[f >> 6];
    }

    float acc[OPT];
#pragma unroll
    for (int j = 0; j < OPT; ++j) acc[j] = 0.0f;

    for (int c = 0; c < NCHUNK; ++c) {
        const int n0 = c * CN;

        __syncthreads();             // previous gather done reading xs
        // ---- commit prefetched chunk c to LDS (ca folded) ----
#pragma unroll
        for (int s = 0; s < SPC; ++s) {
            const int f = (s * 256 + t) * 4;
            const int nrel = f >> 6;
            const int l = f & 63;
            const float cv = cbuf[s];
            float* dst = &xs[nrel * P + l];
            dst[0] = vbuf[s].x * cv;
            dst[1] = vbuf[s].y * cv;
            dst[2] = vbuf[s].z * cv;
            dst[3] = vbuf[s].w * cv;
        }
        __syncthreads();

        // ---- issue chunk c+1 loads NOW; they complete under the gather ----
        if (c + 1 < NCHUNK) {
            const float* __restrict__ src = xrow + (size_t)(n0 + CN) * CASSI_L;
            const float* __restrict__ csrc = carow + (n0 + CN);
#pragma unroll
            for (int s = 0; s < SPC; ++s) {
                const int f = (s * 256 + t) * 4;
                vbuf[s] = *reinterpret_cast<const float4*>(src + f);
                cbuf[s] = csrc[f >> 6];
            }
        }

        // ---- gather chunk c: thread t owns columns o = t + 256*j ----
#pragma unroll
        for (int j = 0; j < OPT; ++j) {
            const int o = t + 256 * j;
            if (o < CASSI_OUTW) {
                const int b = o - n0;            // nrel for l=0
                int llo = b - (CN - 1); if (llo < 0) llo = 0;
                int lhi = b;            if (lhi > 63) lhi = 63;
                if (llo == 0 && lhi == 63) {
                    // interior fast path: full range, 2 chains
                    float s0 = 0.0f, s1 = 0.0f;
#pragma unroll
                    for (int l = 0; l < 64; l += 2) {
                        s0 += xs[(b - l) * P + l];
                        s1 += xs[(b - l - 1) * P + l + 1];
                    }
                    acc[j] += s0 + s1;
                } else if (llo <= lhi) {
                    float s = 0.0f;
                    for (int l = llo; l <= lhi; ++l)
                        s += xs[(b - l) * P + l];
                    acc[j] += s;
                }
            }
        }
    }

    // ---- coalesced writeback ----
    float* __restrict__ orow = out + (size_t)m * CASSI_OUTW;
#pragma unroll
    for (int j = 0; j < OPT; ++j) {
        const int o = t + 256 * j;
        if (o < CASSI_OUTW) orow[o] = acc[j];
    }
}

extern "C" void kernel_launch(void* const* d_in, const int* in_sizes, int n_in,
                              void* d_out, int out_size, void* d_ws, size_t ws_size,
                              hipStream_t stream) {
    const float* x  = (const float*)d_in[0];   // (1, M, N, L)
    const float* ca = (const float*)d_in[1];   // (1, M, N, 1)
    float* out = (float*)d_out;                // (1, M, N+L-1, 1)
    (void)in_sizes; (void)n_in; (void)out_size; (void)d_ws; (void)ws_size;

    cassi_pipe_kernel<<<CASSI_M, 256, 0, stream>>>(x, ca, out);
}

// Round 4
// 357.824 us; speedup vs baseline: 1.0363x; 1.0363x over previous
//
#include <hip/hip_runtime.h>

// CASSI forward: y[m, n+l] += x[m,n,l] * ca[m,n]
// x: (1, M, N, L) fp32, ca: (1, M, N, 1) fp32, y: (1, M, N+L-1, 1) fp32
//
// R3 post-mortem: register prefetch was neutral — the binding constraint is
// the per-chunk barrier convoy: every __syncthreads() drains vmcnt(0) for the
// whole chunk's HBM burst with ~no compute to hide it, and all resident
// blocks march in phase. R4: make chunks INDEPENDENT blocks (grid = M * 8,
// one 128-n chunk each, 512 thr, 33.3 KB LDS -> 4 blocks/CU = 32 waves/CU).
// Blocks at different phases overlap load/gather naturally. Seam overlap
// between adjacent chunks handled with native global_atomic_add_f32 via
// unsafeAtomicAdd (NOT plain atomicAdd -> CAS-loop trap, see R1).
// d_out zeroed by hipMemsetAsync before the scatter kernel.

#define CASSI_M 1024
#define CASSI_N 1024
#define CASSI_L 64
#define CASSI_OUTW (CASSI_N + CASSI_L - 1)  // 1087

constexpr int CN = 128;               // n-columns per block
constexpr int P = CASSI_L + 1;        // 65: padded LDS stride (stride%32==1 -> 2-way max)
constexpr int NCHUNK = CASSI_N / CN;  // 8
constexpr int BLK = 512;              // 8 waves/block; 4 blocks/CU = 32 waves/CU
constexpr int SPC = (CN * CASSI_L) / (BLK * 4);  // 4 float4 per thread
constexpr int OWIN = CN + CASSI_L - 1;           // 191 outputs per block

__global__ __launch_bounds__(BLK) void cassi_chunk_kernel(
    const float* __restrict__ x, const float* __restrict__ ca,
    float* __restrict__ out) {
    __shared__ float xs[CN * P];      // 33,280 B

    const int bid = blockIdx.x;
    const int m = bid >> 3;           // row
    const int c = bid & (NCHUNK - 1); // chunk
    const int n0 = c * CN;
    const int t = threadIdx.x;

    const float* __restrict__ xsrc = x + ((size_t)m * CASSI_N + n0) * CASSI_L;
    const float* __restrict__ csrc = ca + (size_t)m * CASSI_N + n0;

    // ---- stage chunk into LDS, ca folded (coalesced float4 burst) ----
#pragma unroll
    for (int s = 0; s < SPC; ++s) {
        const int f = (s * BLK + t) * 4;     // [0, 8192)
        const int nrel = f >> 6;
        const int l = f & 63;
        const float4 v = *reinterpret_cast<const float4*>(xsrc + f);
        const float cv = csrc[nrel];
        float* dst = &xs[nrel * P + l];
        dst[0] = v.x * cv;
        dst[1] = v.y * cv;
        dst[2] = v.z * cv;
        dst[3] = v.w * cv;
    }
    __syncthreads();

    // ---- gather: thread t owns output column o = n0 + t, t < 191 ----
    if (t < OWIN) {
        const int k = t;
        float s0 = 0.0f, s1 = 0.0f;
#pragma unroll
        for (int l = 0; l < CASSI_L; l += 2) {
            const int n_a = k - l;
            const int n_b = k - l - 1;
            // wrapped address is always in-bounds; invalid lanes masked to 0
            const float va = xs[(n_a & (CN - 1)) * P + l];
            const float vb = xs[(n_b & (CN - 1)) * P + l + 1];
            s0 += ((unsigned)n_a < (unsigned)CN) ? va : 0.0f;
            s1 += ((unsigned)n_b < (unsigned)CN) ? vb : 0.0f;
        }
        // native global fp32 atomic (global_atomic_add_f32)
        unsafeAtomicAdd(&out[(size_t)m * CASSI_OUTW + n0 + k], s0 + s1);
    }
}

extern "C" void kernel_launch(void* const* d_in, const int* in_sizes, int n_in,
                              void* d_out, int out_size, void* d_ws, size_t ws_size,
                              hipStream_t stream) {
    const float* x  = (const float*)d_in[0];   // (1, M, N, L)
    const float* ca = (const float*)d_in[1];   // (1, M, N, 1)
    float* out = (float*)d_out;                // (1, M, N+L-1, 1)
    (void)in_sizes; (void)n_in; (void)d_ws; (void)ws_size;

    hipMemsetAsync(d_out, 0, (size_t)out_size * sizeof(float), stream);
    cassi_chunk_kernel<<<CASSI_M * NCHUNK, BLK, 0, stream>>>(x, ca, out);
}